// Round 2
// baseline (1229.465 us; speedup 1.0000x reference)
//
#include <hip/hip_runtime.h>
#include <hip/hip_bf16.h>
#include <math.h>

#define HID 128
#define EA 16
#define MLP_IN 273      // 1 + 128 + 128 + 16
#define BM 64           // edges per block tile
#define KPAD 280        // padded msg row (16B-aligned rows: 280*4=1120)
#define NTHREADS 256

__device__ __forceinline__ float silu_f(float x) {
    return x * (1.0f / (1.0f + __expf(-x)));
}

__global__ __launch_bounds__(NTHREADS, 2)
void edge_mlp_scatter_kernel(
    const float* __restrict__ node_feat,   // [N][128]
    const float* __restrict__ node_pos,    // [N][3]
    const float* __restrict__ edge_attr,   // [E][16]
    const float* __restrict__ W1,          // [273][128]
    const float* __restrict__ b1,          // [128]
    const float* __restrict__ W2,          // [128][3]
    const float* __restrict__ b2,          // [3]
    const int*   __restrict__ edge_index,  // [2][E]
    float* __restrict__ seg,               // d_out [N][9], pre-zeroed
    float* __restrict__ cnt,               // ws [N], pre-zeroed
    int E)
{
    __shared__ float msg[BM][KPAD];        // 71680 B (aliased as reduction buf later)
    __shared__ float diffb[BM][4];         // dx,dy,dz,dist
    __shared__ float wbuf[BM][3];
    __shared__ int   rowb[BM];

    const int tid = threadIdx.x;

    // ---- Phase 1: stage msg tile [BM][273] into LDS, 4 threads per edge ----
    {
        const int m   = tid >> 2;
        const int sub = tid & 3;
        const long e  = (long)blockIdx.x * BM + m;
        if (e < E) {
            const int row = edge_index[e];
            const int col = edge_index[(long)E + e];
            if (sub == 0) {
                rowb[m] = row;
                float dx = node_pos[row * 3 + 0] - node_pos[col * 3 + 0];
                float dy = node_pos[row * 3 + 1] - node_pos[col * 3 + 1];
                float dz = node_pos[row * 3 + 2] - node_pos[col * 3 + 2];
                float dist = sqrtf(dx * dx + dy * dy + dz * dz);
                diffb[m][0] = dx; diffb[m][1] = dy; diffb[m][2] = dz; diffb[m][3] = dist;
                msg[m][0] = dist;
            }
            const float4* fr = (const float4*)(node_feat + (long)row * HID);
            const float4* fc = (const float4*)(node_feat + (long)col * HID);
            #pragma unroll
            for (int t = 0; t < 8; ++t) {
                const int j = sub * 32 + t * 4;           // 0..124 within feature
                float4 v = fr[j >> 2];
                msg[m][1 + j + 0] = v.x; msg[m][1 + j + 1] = v.y;
                msg[m][1 + j + 2] = v.z; msg[m][1 + j + 3] = v.w;
                float4 u = fc[j >> 2];
                msg[m][129 + j + 0] = u.x; msg[m][129 + j + 1] = u.y;
                msg[m][129 + j + 2] = u.z; msg[m][129 + j + 3] = u.w;
            }
            float4 a = ((const float4*)(edge_attr + (long)e * EA))[sub];
            msg[m][257 + sub * 4 + 0] = a.x; msg[m][257 + sub * 4 + 1] = a.y;
            msg[m][257 + sub * 4 + 2] = a.z; msg[m][257 + sub * 4 + 3] = a.w;
        }
    }
    __syncthreads();

    // ---- Phase 2: H = silu(msg @ W1 + b1), register-tiled fp32 GEMM ----
    const int tx = tid & 31;       // column group: owns cols j0..j0+3
    const int ty = tid >> 5;       // row group: owns rows m0..m0+7
    const int j0 = tx * 4;
    const int m0 = ty * 8;

    float acc[8][4];
    #pragma unroll
    for (int i = 0; i < 8; ++i)
        #pragma unroll
        for (int c = 0; c < 4; ++c) acc[i][c] = 0.0f;

    for (int kt = 0; kt < 68; ++kt) {       // k = 0..271 in steps of 4
        const int k = kt * 4;
        const float4 w0 = *(const float4*)(W1 + (long)(k + 0) * HID + j0);
        const float4 w1 = *(const float4*)(W1 + (long)(k + 1) * HID + j0);
        const float4 w2 = *(const float4*)(W1 + (long)(k + 2) * HID + j0);
        const float4 w3 = *(const float4*)(W1 + (long)(k + 3) * HID + j0);
        #pragma unroll
        for (int i = 0; i < 8; ++i) {
            const float4 a = *(const float4*)(&msg[m0 + i][k]);
            acc[i][0] = fmaf(a.x, w0.x, acc[i][0]);
            acc[i][1] = fmaf(a.x, w0.y, acc[i][1]);
            acc[i][2] = fmaf(a.x, w0.z, acc[i][2]);
            acc[i][3] = fmaf(a.x, w0.w, acc[i][3]);
            acc[i][0] = fmaf(a.y, w1.x, acc[i][0]);
            acc[i][1] = fmaf(a.y, w1.y, acc[i][1]);
            acc[i][2] = fmaf(a.y, w1.z, acc[i][2]);
            acc[i][3] = fmaf(a.y, w1.w, acc[i][3]);
            acc[i][0] = fmaf(a.z, w2.x, acc[i][0]);
            acc[i][1] = fmaf(a.z, w2.y, acc[i][1]);
            acc[i][2] = fmaf(a.z, w2.z, acc[i][2]);
            acc[i][3] = fmaf(a.z, w2.w, acc[i][3]);
            acc[i][0] = fmaf(a.w, w3.x, acc[i][0]);
            acc[i][1] = fmaf(a.w, w3.y, acc[i][1]);
            acc[i][2] = fmaf(a.w, w3.z, acc[i][2]);
            acc[i][3] = fmaf(a.w, w3.w, acc[i][3]);
        }
    }
    {   // tail k = 272
        const float4 wv = *(const float4*)(W1 + (long)272 * HID + j0);
        #pragma unroll
        for (int i = 0; i < 8; ++i) {
            const float a = msg[m0 + i][272];
            acc[i][0] = fmaf(a, wv.x, acc[i][0]);
            acc[i][1] = fmaf(a, wv.y, acc[i][1]);
            acc[i][2] = fmaf(a, wv.z, acc[i][2]);
            acc[i][3] = fmaf(a, wv.w, acc[i][3]);
        }
    }

    // ---- Phase 3: bias + silu, partials of h @ W2 ----
    const float4 bb = *(const float4*)(b1 + j0);
    float w2l[4][3];
    #pragma unroll
    for (int c = 0; c < 4; ++c)
        #pragma unroll
        for (int l = 0; l < 3; ++l)
            w2l[c][l] = W2[(j0 + c) * 3 + l];

    float part[8][3];
    #pragma unroll
    for (int i = 0; i < 8; ++i) {
        const float h0 = silu_f(acc[i][0] + bb.x);
        const float h1 = silu_f(acc[i][1] + bb.y);
        const float h2 = silu_f(acc[i][2] + bb.z);
        const float h3 = silu_f(acc[i][3] + bb.w);
        #pragma unroll
        for (int l = 0; l < 3; ++l)
            part[i][l] = h0 * w2l[0][l] + h1 * w2l[1][l] + h2 * w2l[2][l] + h3 * w2l[3][l];
    }

    __syncthreads();                        // msg reads done; safe to alias
    float* red = &msg[0][0];                // [BM*3][33] reduction buffer (6336 floats)
    #pragma unroll
    for (int i = 0; i < 8; ++i)
        #pragma unroll
        for (int l = 0; l < 3; ++l)
            red[((m0 + i) * 3 + l) * 33 + tx] = part[i][l];
    __syncthreads();

    if (tid < BM * 3) {
        const int mm = tid / 3;
        const int l  = tid % 3;
        const float* rp = red + (size_t)tid * 33;
        float s = 0.0f;
        #pragma unroll
        for (int x = 0; x < 32; ++x) s += rp[x];
        wbuf[mm][l] = silu_f(s + b2[l]);
    }
    __syncthreads();

    // ---- Phase 4: spherical harmonics + weighted scatter (1 thread / edge) ----
    if (tid < BM) {
        const long e = (long)blockIdx.x * BM + tid;
        if (e < E) {
            const int row = rowb[tid];
            const float dx = diffb[tid][0], dy = diffb[tid][1], dz = diffb[tid][2];
            const float dist = diffb[tid][3];
            const float inv = 1.0f / fmaxf(dist, 1e-12f);
            const float x = dx * inv, y = dy * inv, z = dz * inv;
            const float s3 = 1.7320508075688772f;
            float sh[9];
            sh[0] = 1.0f;
            sh[1] = x; sh[2] = y; sh[3] = z;
            sh[4] = s3 * x * z;
            sh[5] = s3 * x * y;
            sh[6] = y * y - 0.5f * (x * x + z * z);
            sh[7] = s3 * y * z;
            sh[8] = 0.5f * s3 * (z * z - x * x);
            const float w0 = wbuf[tid][0], w1 = wbuf[tid][1], w2v = wbuf[tid][2];
            const float wc[9] = { w0, w1, w1, w1, w2v, w2v, w2v, w2v, w2v };
            float* o = seg + (long)row * 9;
            #pragma unroll
            for (int c = 0; c < 9; ++c)
                atomicAdd(o + c, sh[c] * wc[c]);
            atomicAdd(cnt + row, 1.0f);
        }
    }
}

__global__ void finalize_kernel(float* __restrict__ out, const float* __restrict__ cnt, int n_out) {
    const int i = blockIdx.x * blockDim.x + threadIdx.x;
    if (i < n_out) {
        const float c = cnt[i / 9];
        out[i] = out[i] / fmaxf(c, 1.0f);
    }
}

extern "C" void kernel_launch(void* const* d_in, const int* in_sizes, int n_in,
                              void* d_out, int out_size, void* d_ws, size_t ws_size,
                              hipStream_t stream) {
    const float* node_feat  = (const float*)d_in[0];
    const float* node_pos   = (const float*)d_in[1];
    const float* edge_attr  = (const float*)d_in[2];
    const float* W1         = (const float*)d_in[3];
    const float* b1         = (const float*)d_in[4];
    const float* W2         = (const float*)d_in[5];
    const float* b2         = (const float*)d_in[6];
    const int*   edge_index = (const int*)d_in[7];

    const int E = in_sizes[7] / 2;          // edge_index is [2][E]
    const int N = in_sizes[1] / 3;          // node_pos is [N][3]

    float* seg = (float*)d_out;             // [N][9]
    float* cnt = (float*)d_ws;              // [N]

    hipMemsetAsync(d_out, 0, (size_t)out_size * sizeof(float), stream);
    hipMemsetAsync(d_ws, 0, (size_t)N * sizeof(float), stream);

    const int nblocks = (E + BM - 1) / BM;
    edge_mlp_scatter_kernel<<<nblocks, NTHREADS, 0, stream>>>(
        node_feat, node_pos, edge_attr, W1, b1, W2, b2, edge_index,
        seg, cnt, E);

    const int nfin = (out_size + 255) / 256;
    finalize_kernel<<<nfin, 256, 0, stream>>>(seg, cnt, out_size);
}

// Round 3
// 650.570 us; speedup vs baseline: 1.8898x; 1.8898x over previous
//
#include <hip/hip_runtime.h>
#include <hip/hip_bf16.h>
#include <hip/hip_fp16.h>
#include <math.h>

#define HID 128
#define EA 16
#define BM 64            // edges per block tile
#define KP 296           // msg row stride in fp16 (592 B: 16B-aligned, 2-way banks)
#define HP 136           // H row stride in fp16 (272 B: 16B-aligned, 2-way banks)
#define KT1 9            // GEMM1 K-tiles (K padded 273 -> 288)
#define NC 8             // GEMM1 col blocks (128 / 16)
#define NTHREADS 256

#define W1S_OFF 204800           // byte offset of swizzled W1 in d_ws (after cnt[N])
#define W1S_BYTES (KT1 * NC * 64 * 8 * 2)   // 73728
#define W2S_OFF (W1S_OFF + W1S_BYTES)
#define W2S_ELEMS (4 * 64 * 8)              // 2048 fp16

typedef _Float16 half8 __attribute__((ext_vector_type(8)));
typedef _Float16 half4v __attribute__((ext_vector_type(4)));
typedef float floatx4 __attribute__((ext_vector_type(4)));

__device__ __forceinline__ float silu_f(float x) {
    return x * (1.0f / (1.0f + __expf(-x)));
}

// ---------------------------------------------------------------------------
// Kernel 0: pre-swizzle W1 (fp32 [273][128]) and W2 (fp32 [128][3]) into
// fragment-linear fp16 layouts for mfma_f32_16x16x32_f16.
//   msg column permutation: k' < 272 -> original k'+1 ; k' == 272 -> dist (orig 0)
//   fragment (kt, c): lane l holds B[k][n] for k = 32*kt + 8*(l>>4) + i, n = 16*c + (l&15)
//   flat element index: ((kt*8 + c)*64 + lane)*8 + i
// ---------------------------------------------------------------------------
__global__ void precompute_w_kernel(const float* __restrict__ W1,
                                    const float* __restrict__ W2,
                                    _Float16* __restrict__ w1s,
                                    _Float16* __restrict__ w2s) {
    const int idx = blockIdx.x * NTHREADS + threadIdx.x;
    if (idx < KT1 * NC * 64 * 8) {
        const int i    = idx & 7;
        const int lane = (idx >> 3) & 63;
        const int c    = (idx >> 9) & 7;
        const int kt   = idx >> 12;
        const int k    = kt * 32 + (lane >> 4) * 8 + i;
        const int n    = c * 16 + (lane & 15);
        float v = 0.0f;
        if (k < 273) {
            const int src = (k < 272) ? (k + 1) : 0;
            v = W1[src * HID + n];
        }
        w1s[idx] = (_Float16)v;
    }
    if (idx < W2S_ELEMS) {
        const int i    = idx & 7;
        const int lane = (idx >> 3) & 63;
        const int kt   = idx >> 9;
        const int k    = kt * 32 + (lane >> 4) * 8 + i;
        const int n    = lane & 15;
        const float v  = (n < 3) ? W2[k * 3 + n] : 0.0f;
        w2s[idx] = (_Float16)v;
    }
}

// ---------------------------------------------------------------------------
// Fused: gather -> msg fp16 tile -> MFMA GEMM1 -> silu -> MFMA GEMM2 -> silu
//        -> spherical harmonics -> atomic scatter
// ---------------------------------------------------------------------------
__global__ __launch_bounds__(NTHREADS, 4)
void edge_mlp_scatter_kernel(
    const float* __restrict__ node_feat,   // [N][128]
    const float* __restrict__ node_pos,    // [N][3]
    const float* __restrict__ edge_attr,   // [E][16]
    const float* __restrict__ b1,          // [128]
    const float* __restrict__ b2,          // [3]
    const int*   __restrict__ edge_index,  // [2][E]
    const _Float16* __restrict__ w1s,      // swizzled fp16 W1
    const _Float16* __restrict__ w2s,      // swizzled fp16 W2
    float* __restrict__ seg,               // d_out [N][9], pre-zeroed
    float* __restrict__ cnt,               // ws [N], pre-zeroed
    int E)
{
    __shared__ _Float16 msg[BM][KP];       // 37888 B; aliased as H[BM][HP] later
    __shared__ float diffb[BM][4];         // dx,dy,dz,dist
    __shared__ float wbuf[BM][3];
    __shared__ int   rowb[BM];

    const int tid = threadIdx.x;

    // ---- Phase 1: stage msg tile [BM][288] fp16 into LDS, 4 threads/edge ----
    {
        const int m   = tid >> 2;
        const int sub = tid & 3;
        const long e  = (long)blockIdx.x * BM + m;
        if (e < E) {
            const int row = edge_index[e];
            const int col = edge_index[(long)E + e];
            _Float16* mrow = &msg[m][0];
            if (sub == 0) {
                rowb[m] = row;
                const float dx = node_pos[row * 3 + 0] - node_pos[col * 3 + 0];
                const float dy = node_pos[row * 3 + 1] - node_pos[col * 3 + 1];
                const float dz = node_pos[row * 3 + 2] - node_pos[col * 3 + 2];
                const float dist = sqrtf(dx * dx + dy * dy + dz * dz);
                diffb[m][0] = dx; diffb[m][1] = dy; diffb[m][2] = dz; diffb[m][3] = dist;
                half8 z = { (_Float16)dist, (_Float16)0.f, (_Float16)0.f, (_Float16)0.f,
                            (_Float16)0.f, (_Float16)0.f, (_Float16)0.f, (_Float16)0.f };
                *(half8*)(mrow + 272) = z;          // dist @272, zeros 273..279
            } else if (sub == 1) {
                half8 z = { (_Float16)0.f, (_Float16)0.f, (_Float16)0.f, (_Float16)0.f,
                            (_Float16)0.f, (_Float16)0.f, (_Float16)0.f, (_Float16)0.f };
                *(half8*)(mrow + 280) = z;          // zeros 280..287
            }
            const float4* fr = (const float4*)(node_feat + (long)row * HID);
            const float4* fc = (const float4*)(node_feat + (long)col * HID);
            #pragma unroll
            for (int t = 0; t < 4; ++t) {
                float4 a = fr[sub * 8 + 2 * t];
                float4 b = fr[sub * 8 + 2 * t + 1];
                half8 h = { (_Float16)a.x, (_Float16)a.y, (_Float16)a.z, (_Float16)a.w,
                            (_Float16)b.x, (_Float16)b.y, (_Float16)b.z, (_Float16)b.w };
                *(half8*)(mrow + sub * 32 + t * 8) = h;
            }
            #pragma unroll
            for (int t = 0; t < 4; ++t) {
                float4 a = fc[sub * 8 + 2 * t];
                float4 b = fc[sub * 8 + 2 * t + 1];
                half8 h = { (_Float16)a.x, (_Float16)a.y, (_Float16)a.z, (_Float16)a.w,
                            (_Float16)b.x, (_Float16)b.y, (_Float16)b.z, (_Float16)b.w };
                *(half8*)(mrow + 128 + sub * 32 + t * 8) = h;
            }
            float4 ea = ((const float4*)(edge_attr + (long)e * EA))[sub];
            half4v h4 = { (_Float16)ea.x, (_Float16)ea.y, (_Float16)ea.z, (_Float16)ea.w };
            *(half4v*)(mrow + 256 + sub * 4) = h4;
        }
    }
    __syncthreads();

    // ---- Phase 2: H = msg @ W1 via MFMA. Wave w owns col-blocks {2w, 2w+1}. ----
    const int wave = tid >> 6;
    const int lane = tid & 63;
    const int lrow = lane & 15;     // A row-offset within row-block / D col
    const int g    = lane >> 4;     // k-group / D row-quad

    floatx4 acc[4][2];
    #pragma unroll
    for (int rb = 0; rb < 4; ++rb) {
        acc[rb][0] = (floatx4){0.f, 0.f, 0.f, 0.f};
        acc[rb][1] = (floatx4){0.f, 0.f, 0.f, 0.f};
    }

    #pragma unroll
    for (int kt = 0; kt < KT1; ++kt) {
        const half8 bf0 = *(const half8*)(w1s + ((size_t)((kt * NC + 2 * wave + 0) * 64 + lane)) * 8);
        const half8 bf1 = *(const half8*)(w1s + ((size_t)((kt * NC + 2 * wave + 1) * 64 + lane)) * 8);
        #pragma unroll
        for (int rb = 0; rb < 4; ++rb) {
            const half8 af = *(const half8*)&msg[16 * rb + lrow][kt * 32 + g * 8];
            acc[rb][0] = __builtin_amdgcn_mfma_f32_16x16x32_f16(af, bf0, acc[rb][0], 0, 0, 0);
            acc[rb][1] = __builtin_amdgcn_mfma_f32_16x16x32_f16(af, bf1, acc[rb][1], 0, 0, 0);
        }
    }

    // ---- Phase 3: bias + silu, write H fp16 tile (aliases msg) ----
    const int col0 = 32 * wave + lrow;       // D col of acc[rb][0]
    const int col1 = col0 + 16;              // D col of acc[rb][1]
    const float bb0 = b1[col0];
    const float bb1 = b1[col1];

    __syncthreads();                          // all waves done reading msg
    _Float16* Hb = &msg[0][0];                // H[64][HP]
    #pragma unroll
    for (int rb = 0; rb < 4; ++rb) {
        #pragma unroll
        for (int reg = 0; reg < 4; ++reg) {
            const int r = 16 * rb + 4 * g + reg;   // D row
            Hb[r * HP + col0] = (_Float16)silu_f(acc[rb][0][reg] + bb0);
            Hb[r * HP + col1] = (_Float16)silu_f(acc[rb][1][reg] + bb1);
        }
    }
    __syncthreads();

    // ---- Phase 4: w = silu(H @ W2 + b2) via MFMA. Wave w owns row-block w. ----
    floatx4 acc2 = (floatx4){0.f, 0.f, 0.f, 0.f};
    #pragma unroll
    for (int kt = 0; kt < 4; ++kt) {
        const half8 af = *(const half8*)(Hb + (16 * wave + lrow) * HP + kt * 32 + g * 8);
        const half8 bf = *(const half8*)(w2s + ((size_t)(kt * 64 + lane)) * 8);
        acc2 = __builtin_amdgcn_mfma_f32_16x16x32_f16(af, bf, acc2, 0, 0, 0);
    }
    if (lrow < 3) {
        const float bb2 = b2[lrow];
        #pragma unroll
        for (int reg = 0; reg < 4; ++reg)
            wbuf[16 * wave + 4 * g + reg][lrow] = silu_f(acc2[reg] + bb2);
    }
    __syncthreads();

    // ---- Phase 5: spherical harmonics + weighted scatter (1 thread / edge) ----
    if (tid < BM) {
        const long e = (long)blockIdx.x * BM + tid;
        if (e < E) {
            const int row = rowb[tid];
            const float dx = diffb[tid][0], dy = diffb[tid][1], dz = diffb[tid][2];
            const float dist = diffb[tid][3];
            const float inv = 1.0f / fmaxf(dist, 1e-12f);
            const float x = dx * inv, y = dy * inv, z = dz * inv;
            const float s3 = 1.7320508075688772f;
            float sh[9];
            sh[0] = 1.0f;
            sh[1] = x; sh[2] = y; sh[3] = z;
            sh[4] = s3 * x * z;
            sh[5] = s3 * x * y;
            sh[6] = y * y - 0.5f * (x * x + z * z);
            sh[7] = s3 * y * z;
            sh[8] = 0.5f * s3 * (z * z - x * x);
            const float w0 = wbuf[tid][0], w1 = wbuf[tid][1], w2v = wbuf[tid][2];
            const float wc[9] = { w0, w1, w1, w1, w2v, w2v, w2v, w2v, w2v };
            float* o = seg + (long)row * 9;
            #pragma unroll
            for (int c = 0; c < 9; ++c)
                atomicAdd(o + c, sh[c] * wc[c]);
            atomicAdd(cnt + row, 1.0f);
        }
    }
}

__global__ void finalize_kernel(float* __restrict__ out, const float* __restrict__ cnt, int n_out) {
    const int i = blockIdx.x * blockDim.x + threadIdx.x;
    if (i < n_out) {
        const float c = cnt[i / 9];
        out[i] = out[i] / fmaxf(c, 1.0f);
    }
}

extern "C" void kernel_launch(void* const* d_in, const int* in_sizes, int n_in,
                              void* d_out, int out_size, void* d_ws, size_t ws_size,
                              hipStream_t stream) {
    const float* node_feat  = (const float*)d_in[0];
    const float* node_pos   = (const float*)d_in[1];
    const float* edge_attr  = (const float*)d_in[2];
    const float* W1         = (const float*)d_in[3];
    const float* b1         = (const float*)d_in[4];
    const float* W2         = (const float*)d_in[5];
    const float* b2         = (const float*)d_in[6];
    const int*   edge_index = (const int*)d_in[7];

    const int E = in_sizes[7] / 2;          // edge_index is [2][E]
    const int N = in_sizes[1] / 3;          // node_pos is [N][3]

    float* seg = (float*)d_out;             // [N][9]
    float* cnt = (float*)d_ws;              // [N]
    _Float16* w1s = (_Float16*)((char*)d_ws + W1S_OFF);
    _Float16* w2s = (_Float16*)((char*)d_ws + W2S_OFF);

    hipMemsetAsync(d_out, 0, (size_t)out_size * sizeof(float), stream);
    hipMemsetAsync(d_ws, 0, (size_t)N * sizeof(float), stream);

    const int n_pre = KT1 * NC * 64 * 8;    // 36864 threads cover both tables
    precompute_w_kernel<<<(n_pre + NTHREADS - 1) / NTHREADS, NTHREADS, 0, stream>>>(
        W1, W2, w1s, w2s);

    const int nblocks = (E + BM - 1) / BM;
    edge_mlp_scatter_kernel<<<nblocks, NTHREADS, 0, stream>>>(
        node_feat, node_pos, edge_attr, b1, b2, edge_index, w1s, w2s,
        seg, cnt, E);

    const int nfin = (out_size + 255) / 256;
    finalize_kernel<<<nfin, 256, 0, stream>>>(seg, cnt, out_size);
}

// Round 4
// 646.046 us; speedup vs baseline: 1.9031x; 1.0070x over previous
//
#include <hip/hip_runtime.h>
#include <hip/hip_bf16.h>
#include <hip/hip_fp16.h>
#include <math.h>

#define HID 128
#define EA 16
#define BM 64            // edges per block tile
#define KP 296           // msg row stride in fp16 (592 B)
#define HP 136           // H row stride in fp16 (272 B)
#define KT1 9            // GEMM1 K-tiles (K padded 273 -> 288)
#define NC 8             // GEMM1 col blocks (128 / 16)
#define NTHREADS 256
#define NBLOCKS 1024     // 4 blocks/CU x 256 CUs, grid-stride over tiles

// workspace layout (bytes)
#define W1S_OFF   204800                    // after cnt[N] floats
#define W1S_ELEMS (KT1 * NC * 64 * 8)       // 36864 fp16
#define W2S_OFF   (W1S_OFF + W1S_ELEMS * 2) // 278528
#define W2S_ELEMS (4 * 64 * 8)              // 2048 fp16
#define FEAT16_OFF 524288                   // N*HID fp16 = 12.8 MB

typedef _Float16 half8 __attribute__((ext_vector_type(8)));
typedef _Float16 half4v __attribute__((ext_vector_type(4)));
typedef float floatx4 __attribute__((ext_vector_type(4)));

__device__ __forceinline__ float silu_f(float x) {
    return x * (1.0f / (1.0f + __expf(-x)));
}

// ---------------------------------------------------------------------------
// Prep: swizzle W1/W2 to fp16 fragment-linear layout, convert node_feat to
// fp16, zero seg + cnt.  Replaces two memsets + old precompute (fewer
// dispatches).
// ---------------------------------------------------------------------------
__global__ void prep_kernel(const float* __restrict__ W1,
                            const float* __restrict__ W2,
                            const float* __restrict__ node_feat,
                            _Float16* __restrict__ w1s,
                            _Float16* __restrict__ w2s,
                            _Float16* __restrict__ feat16,
                            float* __restrict__ seg,
                            float* __restrict__ cnt,
                            int nf8, int nseg, int ncnt) {
    const int idx = blockIdx.x * NTHREADS + threadIdx.x;
    if (idx < W1S_ELEMS) {
        const int i    = idx & 7;
        const int lane = (idx >> 3) & 63;
        const int c    = (idx >> 9) & 7;
        const int kt   = idx >> 12;
        const int k    = kt * 32 + (lane >> 4) * 8 + i;
        const int n    = c * 16 + (lane & 15);
        float v = 0.0f;
        if (k < 273) {
            const int src = (k < 272) ? (k + 1) : 0;   // col-permuted: dist last
            v = W1[src * HID + n];
        }
        w1s[idx] = (_Float16)v;
    }
    if (idx < W2S_ELEMS) {
        const int i    = idx & 7;
        const int lane = (idx >> 3) & 63;
        const int kt   = idx >> 9;
        const int k    = kt * 32 + (lane >> 4) * 8 + i;
        const int n    = lane & 15;
        const float v  = (n < 3) ? W2[k * 3 + n] : 0.0f;
        w2s[idx] = (_Float16)v;
    }
    if (idx < nf8) {
        const float4* src = (const float4*)node_feat;
        const float4 a = src[2 * idx];
        const float4 b = src[2 * idx + 1];
        half8 h = { (_Float16)a.x, (_Float16)a.y, (_Float16)a.z, (_Float16)a.w,
                    (_Float16)b.x, (_Float16)b.y, (_Float16)b.z, (_Float16)b.w };
        ((half8*)feat16)[idx] = h;
    }
    if (idx < nseg) seg[idx] = 0.0f;
    if (idx < ncnt) cnt[idx] = 0.0f;
}

// ---------------------------------------------------------------------------
// Fused main kernel: grid-stride over 64-edge tiles with register prefetch
// (T14 async-STAGE split): tile t+1's gathers are issued after GEMM1 and fly
// under phase3/GEMM2/scatter; the vmcnt wait lands at next iteration's LDS
// staging write.
// ---------------------------------------------------------------------------
__global__ __launch_bounds__(NTHREADS, 4)
void edge_mlp_scatter_kernel(
    const _Float16* __restrict__ feat16,   // [N][128] fp16
    const float* __restrict__ node_pos,    // [N][3]
    const float* __restrict__ edge_attr,   // [E][16]
    const float* __restrict__ b1,          // [128]
    const float* __restrict__ b2,          // [3]
    const int*   __restrict__ edge_index,  // [2][E]
    const _Float16* __restrict__ w1s,      // swizzled fp16 W1
    const _Float16* __restrict__ w2s,      // swizzled fp16 W2
    float* __restrict__ seg,               // d_out [N][9], zeroed by prep
    float* __restrict__ cnt,               // ws [N], zeroed by prep
    int E, int ntiles)
{
    __shared__ _Float16 msg[BM][KP];       // 37888 B; aliased: H[64][HP] + shw
    __shared__ float diffb[BM][4];
    __shared__ float wbuf[BM][3];
    __shared__ int   rowb[BM];
    float* shw = (float*)(&msg[0][0] + BM * HP);   // [BM][10] @ byte 17408, past H

    const int tid  = threadIdx.x;
    const int m    = tid >> 2;      // edge within tile
    const int sub  = tid & 3;       // quarter of the msg row
    const int wave = tid >> 6;
    const int lane = tid & 63;
    const int lrow = lane & 15;
    const int g    = lane >> 4;

    // ---- staged registers for the NEXT tile ----
    int   s_row = 0, s_col = 0;
    half8 s_fr[4], s_fc[4];
    float4 s_ea;
    float s_p0 = 0, s_p1 = 0, s_p2 = 0, s_q0 = 0, s_q1 = 0, s_q2 = 0;

    // ---- prologue: issue loads for this block's first tile ----
    {
        const long e  = (long)blockIdx.x * BM + m;
        const long ec = e < E ? e : 0;
        s_row = edge_index[ec];
        s_col = edge_index[(long)E + ec];
        const half8* fr = (const half8*)(feat16 + (long)s_row * HID);
        const half8* fc = (const half8*)(feat16 + (long)s_col * HID);
        #pragma unroll
        for (int t = 0; t < 4; ++t) { s_fr[t] = fr[sub * 4 + t]; s_fc[t] = fc[sub * 4 + t]; }
        s_ea = ((const float4*)(edge_attr + ec * EA))[sub];
        if (sub == 0) {
            s_p0 = node_pos[(long)s_row * 3 + 0];
            s_p1 = node_pos[(long)s_row * 3 + 1];
            s_p2 = node_pos[(long)s_row * 3 + 2];
            s_q0 = node_pos[(long)s_col * 3 + 0];
            s_q1 = node_pos[(long)s_col * 3 + 1];
            s_q2 = node_pos[(long)s_col * 3 + 2];
        }
    }

    for (int tile = blockIdx.x; tile < ntiles; tile += NBLOCKS) {
        __syncthreads();                       // (A) prev iter's LDS consumers done

        // ---- stage write: regs -> LDS (waits on the in-flight gathers) ----
        {
            _Float16* mrow = &msg[m][0];
            #pragma unroll
            for (int t = 0; t < 4; ++t) {
                *(half8*)(mrow +       sub * 32 + t * 8) = s_fr[t];
                *(half8*)(mrow + 128 + sub * 32 + t * 8) = s_fc[t];
            }
            half4v h4 = { (_Float16)s_ea.x, (_Float16)s_ea.y,
                          (_Float16)s_ea.z, (_Float16)s_ea.w };
            *(half4v*)(mrow + 256 + sub * 4) = h4;
            if (sub == 0) {
                rowb[m] = s_row;
                const float dx = s_p0 - s_q0, dy = s_p1 - s_q1, dz = s_p2 - s_q2;
                const float dist = sqrtf(dx * dx + dy * dy + dz * dz);
                diffb[m][0] = dx; diffb[m][1] = dy; diffb[m][2] = dz; diffb[m][3] = dist;
                half8 z = { (_Float16)dist, (_Float16)0.f, (_Float16)0.f, (_Float16)0.f,
                            (_Float16)0.f, (_Float16)0.f, (_Float16)0.f, (_Float16)0.f };
                *(half8*)(mrow + 272) = z;
            } else if (sub == 1) {
                half8 z = { (_Float16)0.f, (_Float16)0.f, (_Float16)0.f, (_Float16)0.f,
                            (_Float16)0.f, (_Float16)0.f, (_Float16)0.f, (_Float16)0.f };
                *(half8*)(mrow + 280) = z;
            }
        }
        __syncthreads();                       // (B) msg ready

        // ---- prefetch next tile's indices (latency hides under GEMM1) ----
        const int  nt = tile + NBLOCKS;
        const bool have_next = nt < ntiles;
        if (have_next) {
            const long e  = (long)nt * BM + m;
            const long ec = e < E ? e : 0;
            s_row = edge_index[ec];
            s_col = edge_index[(long)E + ec];
        }

        // ---- GEMM1: H = msg @ W1, wave owns col-blocks {2w, 2w+1} ----
        floatx4 acc[4][2];
        #pragma unroll
        for (int rb = 0; rb < 4; ++rb) {
            acc[rb][0] = (floatx4){0.f, 0.f, 0.f, 0.f};
            acc[rb][1] = (floatx4){0.f, 0.f, 0.f, 0.f};
        }
        #pragma unroll
        for (int kt = 0; kt < KT1; ++kt) {
            const half8 bf0 = *(const half8*)(w1s + ((size_t)((kt * NC + 2 * wave + 0) * 64 + lane)) * 8);
            const half8 bf1 = *(const half8*)(w1s + ((size_t)((kt * NC + 2 * wave + 1) * 64 + lane)) * 8);
            #pragma unroll
            for (int rb = 0; rb < 4; ++rb) {
                const half8 af = *(const half8*)&msg[16 * rb + lrow][kt * 32 + g * 8];
                acc[rb][0] = __builtin_amdgcn_mfma_f32_16x16x32_f16(af, bf0, acc[rb][0], 0, 0, 0);
                acc[rb][1] = __builtin_amdgcn_mfma_f32_16x16x32_f16(af, bf1, acc[rb][1], 0, 0, 0);
            }
        }

        // ---- issue next tile's gathers; they fly under phase3/GEMM2/scatter ----
        if (have_next) {
            const long e  = (long)nt * BM + m;
            const long ec = e < E ? e : 0;
            const half8* fr = (const half8*)(feat16 + (long)s_row * HID);
            const half8* fc = (const half8*)(feat16 + (long)s_col * HID);
            #pragma unroll
            for (int t = 0; t < 4; ++t) { s_fr[t] = fr[sub * 4 + t]; s_fc[t] = fc[sub * 4 + t]; }
            s_ea = ((const float4*)(edge_attr + ec * EA))[sub];
            if (sub == 0) {
                s_p0 = node_pos[(long)s_row * 3 + 0];
                s_p1 = node_pos[(long)s_row * 3 + 1];
                s_p2 = node_pos[(long)s_row * 3 + 2];
                s_q0 = node_pos[(long)s_col * 3 + 0];
                s_q1 = node_pos[(long)s_col * 3 + 1];
                s_q2 = node_pos[(long)s_col * 3 + 2];
            }
        }

        __syncthreads();                       // (C) all GEMM1 msg reads done
        // ---- phase3: bias + silu, H fp16 tile (aliases msg) ----
        {
            const int col0 = 32 * wave + lrow;
            const int col1 = col0 + 16;
            const float bb0 = b1[col0];
            const float bb1 = b1[col1];
            _Float16* Hb = &msg[0][0];
            #pragma unroll
            for (int rb = 0; rb < 4; ++rb) {
                #pragma unroll
                for (int reg = 0; reg < 4; ++reg) {
                    const int r = 16 * rb + 4 * g + reg;
                    Hb[r * HP + col0] = (_Float16)silu_f(acc[rb][0][reg] + bb0);
                    Hb[r * HP + col1] = (_Float16)silu_f(acc[rb][1][reg] + bb1);
                }
            }
        }
        __syncthreads();                       // (D)

        // ---- GEMM2: w = silu(H @ W2 + b2), wave owns row-block w ----
        {
            floatx4 acc2 = (floatx4){0.f, 0.f, 0.f, 0.f};
            const _Float16* Hb = &msg[0][0];
            #pragma unroll
            for (int kt = 0; kt < 4; ++kt) {
                const half8 af = *(const half8*)(Hb + (16 * wave + lrow) * HP + kt * 32 + g * 8);
                const half8 bf = *(const half8*)(w2s + ((size_t)(kt * 64 + lane)) * 8);
                acc2 = __builtin_amdgcn_mfma_f32_16x16x32_f16(af, bf, acc2, 0, 0, 0);
            }
            if (lrow < 3) {
                const float bb2 = b2[lrow];
                #pragma unroll
                for (int reg = 0; reg < 4; ++reg)
                    wbuf[16 * wave + 4 * g + reg][lrow] = silu_f(acc2[reg] + bb2);
            }
        }
        __syncthreads();                       // (E)

        // ---- spherical harmonics -> shw LDS (1 thread/edge) ----
        if (tid < BM) {
            const float dx = diffb[tid][0], dy = diffb[tid][1], dz = diffb[tid][2];
            const float dist = diffb[tid][3];
            const float inv = 1.0f / fmaxf(dist, 1e-12f);
            const float x = dx * inv, y = dy * inv, z = dz * inv;
            const float s3 = 1.7320508075688772f;
            const float w0 = wbuf[tid][0], w1 = wbuf[tid][1], w2v = wbuf[tid][2];
            float* o = shw + tid * 10;
            o[0] = w0;
            o[1] = x * w1; o[2] = y * w1; o[3] = z * w1;
            o[4] = s3 * x * z * w2v;
            o[5] = s3 * x * y * w2v;
            o[6] = (y * y - 0.5f * (x * x + z * z)) * w2v;
            o[7] = s3 * y * z * w2v;
            o[8] = 0.5f * s3 * (z * z - x * x) * w2v;
            o[9] = 1.0f;
        }
        __syncthreads();                       // (F)

        // ---- scatter: 640 ops spread over all 256 threads, coalesced ----
        const long ebase = (long)tile * BM;
        #pragma unroll
        for (int oo = 0; oo < 3; ++oo) {
            const int op = tid + oo * NTHREADS;
            if (op < BM * 10) {
                const int mm = op / 10;
                const int c  = op - mm * 10;
                if (ebase + mm < E) {
                    const int row = rowb[mm];
                    if (c < 9) atomicAdd(seg + (long)row * 9 + c, shw[op]);
                    else       atomicAdd(cnt + row, 1.0f);
                }
            }
        }
    }
}

__global__ void finalize_kernel(float* __restrict__ out, const float* __restrict__ cnt, int n_out) {
    const int i = blockIdx.x * blockDim.x + threadIdx.x;
    if (i < n_out) {
        const float c = cnt[i / 9];
        out[i] = out[i] / fmaxf(c, 1.0f);
    }
}

extern "C" void kernel_launch(void* const* d_in, const int* in_sizes, int n_in,
                              void* d_out, int out_size, void* d_ws, size_t ws_size,
                              hipStream_t stream) {
    const float* node_feat  = (const float*)d_in[0];
    const float* node_pos   = (const float*)d_in[1];
    const float* edge_attr  = (const float*)d_in[2];
    const float* W1         = (const float*)d_in[3];
    const float* b1         = (const float*)d_in[4];
    const float* W2         = (const float*)d_in[5];
    const float* b2         = (const float*)d_in[6];
    const int*   edge_index = (const int*)d_in[7];

    const int E = in_sizes[7] / 2;          // edge_index is [2][E]
    const int N = in_sizes[1] / 3;          // node_pos is [N][3]
    const int ntiles = (E + BM - 1) / BM;

    float*    seg    = (float*)d_out;       // [N][9]
    float*    cnt    = (float*)d_ws;        // [N]
    _Float16* w1s    = (_Float16*)((char*)d_ws + W1S_OFF);
    _Float16* w2s    = (_Float16*)((char*)d_ws + W2S_OFF);
    _Float16* feat16 = (_Float16*)((char*)d_ws + FEAT16_OFF);

    const int nf8   = N * HID / 8;          // 800000 half8 conversions
    int nprep = nf8 > out_size ? nf8 : out_size;
    if (nprep < W1S_ELEMS) nprep = W1S_ELEMS;
    prep_kernel<<<(nprep + NTHREADS - 1) / NTHREADS, NTHREADS, 0, stream>>>(
        W1, W2, node_feat, w1s, w2s, feat16, seg, cnt, nf8, out_size, N);

    edge_mlp_scatter_kernel<<<NBLOCKS, NTHREADS, 0, stream>>>(
        feat16, node_pos, edge_attr, b1, b2, edge_index, w1s, w2s,
        seg, cnt, E, ntiles);

    const int nfin = (out_size + 255) / 256;
    finalize_kernel<<<nfin, 256, 0, stream>>>(seg, cnt, out_size);
}